// Round 7
// baseline (192.748 us; speedup 1.0000x reference)
//
#include <hip/hip_runtime.h>
#include <hip/hip_bf16.h>

#define NB    8192
#define NF    50
#define NE    64
#define STR   72            // LDS row stride in bf16 elems (144 B)

typedef __attribute__((ext_vector_type(8))) short short8;   // 8 x bf16 MFMA A/B frag
typedef __attribute__((ext_vector_type(4))) short short4v;  // 4 x bf16 packed store
typedef __attribute__((ext_vector_type(4))) float float4v;  // MFMA C/D frag

static constexpr float SM_C   = 0.25509667991878083f; // (1/sqrt(32)) * log2(e), folded into Wk
static constexpr float LN_EPS = 1e-6f;

#define MFMA(a, b, c) __builtin_amdgcn_mfma_f32_16x16x32_bf16((a), (b), (c), 0, 0, 0)

__device__ __forceinline__ unsigned short f2bf(float f) {
    return __bfloat16_as_ushort(__float2bfloat16(f));  // native RNE cvt
}

__device__ __forceinline__ void st_pack4(unsigned short* p, float4v v) {
    union { unsigned short u[4]; short4v s; } r;
    r.u[0] = f2bf(v.x); r.u[1] = f2bf(v.y); r.u[2] = f2bf(v.z); r.u[3] = f2bf(v.w);
    *(short4v*)p = r.s;   // ds_write_b64
}

__device__ __forceinline__ float fexp2(float x) {
#if __has_builtin(__builtin_amdgcn_exp2f)
    return __builtin_amdgcn_exp2f(x);
#else
    float r; asm("v_exp_f32 %0, %1" : "=v"(r) : "v"(x)); return r;
#endif
}

__device__ __forceinline__ float frcp(float x) {
#if __has_builtin(__builtin_amdgcn_rcpf)
    return __builtin_amdgcn_rcpf(x);
#else
    return 1.f / x;
#endif
}

// ---- prep: transpose all weights to bf16 [mat][o][e] = W[e][o] in d_ws ----
// slots 0..7 = Wq domains (o-PERMUTED, see pi below), 8 = Wk (pre-scaled by SM_C),
// 9 = Wv, 10 = Wr.
// pi: stored row o' holds original output-col pi(o') so the Q-projection's
// accumulator registers land exactly in score-MFMA B-fragment order
// (o' = 32h+16t+4lg+r  ->  d = 32h+8lg+4t+r).
__global__ void prep_weights(const float* __restrict__ wq, const float* __restrict__ wk,
                             const float* __restrict__ wv, const float* __restrict__ wr,
                             unsigned short* __restrict__ ws) {
    int i = blockIdx.x * 256 + threadIdx.x;
    if (i >= 11 * 4096) return;
    int m = i >> 12, t = i & 4095, o = t >> 6, e = t & 63;
    float v;
    if (m < 8) {
        int po = (o & 32) | ((o & 12) << 1) | (((o >> 4) & 1) << 2) | (o & 3);
        v = wq[(m * 64 + e) * 64 + po];
    }
    else if (m == 8) v = wk[e * 64 + o] * SM_C;   // fold softmax scale (and log2e) into K
    else if (m == 9) v = wv[e * 64 + o];
    else             v = wr[e * 64 + o];
    ws[i] = f2bf(v);
}

__global__ __launch_bounds__(256, 5)
void mdr_mfma(const float* __restrict__ x_g, const int* __restrict__ dom_g,
              const unsigned short* __restrict__ ws,
              const float* __restrict__ gam_g, const float* __restrict__ bet_g,
              float* __restrict__ out_g) {
    __shared__ __align__(16) unsigned short L[3 * NE * STR];   // 27648 B -> 5 blocks/CU
    unsigned short* xs = L;                 // x rowmajor [64][STR]
    unsigned short* Kb = L + NE * STR;      // K rowmajor [j][d]
    unsigned short* Vt = L + 2 * NE * STR;  // V^T [e][tau-permuted j]

    const int tid = threadIdx.x;
    const int lm  = tid & 15;        // lane & 15
    const int lg  = (tid >> 4) & 3;  // lane >> 4 within wave
    const int w   = tid >> 6;        // wave 0..3
    const int b   = blockIdx.x;

    const int dom = dom_g[b] - 1;

    // ---------------- stage x (f32 -> bf16, rows >= NF zeroed) ----------------
    {
        const float* xb = x_g + (size_t)b * (NF * NE);
        #pragma unroll
        for (int it = 0; it < 4; ++it) {
            int s = tid + it * 256;          // 0..1023 : row = s>>4, c4 = s&15
            int r = s >> 4, c4 = s & 15;
            float4v v = {0.f, 0.f, 0.f, 0.f};
            if (r < NF) v = *(const float4v*)(xb + s * 4);
            st_pack4(xs + r * STR + c4 * 4, v);
        }
    }
    __syncthreads();   // barrier 1: xs staged

    // ---------------- x fragments (from LDS) ----------------
    short8 xf[4][2];
    #pragma unroll
    for (int t = 0; t < 4; ++t)
        #pragma unroll
        for (int ks = 0; ks < 2; ++ks)
            xf[t][ks] = *(const short8*)(xs + (lm + 16 * t) * STR + 8 * lg + 32 * ks);

    // ---------------- Q^T = Wq'^T x^T  (registers only; pi-permuted Wq) ----------------
    // qacc[mt'=2h+t] reg r at lane (lm,lg) = Q[f=16w+lm][d=32h+8lg+4t+r]
    short8 qfrag[2];     // score B-frag per head: [d=32h+8lg .. +7] @ f=16w+lm
    {
        const unsigned short* wq = ws + dom * 4096;
        float4v qacc[4];
        #pragma unroll
        for (int mt = 0; mt < 4; ++mt) {
            short8 qw0 = *(const short8*)(wq + (lm + 16 * mt) * 64 + 8 * lg);
            short8 qw1 = *(const short8*)(wq + (lm + 16 * mt) * 64 + 8 * lg + 32);
            float4v acc = {0.f, 0.f, 0.f, 0.f};
            acc = MFMA(qw0, xf[w][0], acc);
            acc = MFMA(qw1, xf[w][1], acc);
            qacc[mt] = acc;
        }
        #pragma unroll
        for (int h = 0; h < 2; ++h) {
            union { unsigned short u[8]; short8 s; } r;
            #pragma unroll
            for (int r4 = 0; r4 < 4; ++r4) {
                r.u[r4]     = f2bf(qacc[2 * h][r4]);
                r.u[4 + r4] = f2bf(qacc[2 * h + 1][r4]);
            }
            qfrag[h] = r.s;
        }
    }
    // ---------------- K^T = Wk^T x^T  (write rowmajor K; rows >= NF exactly 0) ----------------
    {
        const unsigned short* wk = ws + 8 * 4096;
        #pragma unroll
        for (int mt = 0; mt < 4; ++mt) {
            short8 kw0 = *(const short8*)(wk + (lm + 16 * mt) * 64 + 8 * lg);
            short8 kw1 = *(const short8*)(wk + (lm + 16 * mt) * 64 + 8 * lg + 32);
            float4v acc = {0.f, 0.f, 0.f, 0.f};
            acc = MFMA(kw0, xf[w][0], acc);
            acc = MFMA(kw1, xf[w][1], acc);
            st_pack4(Kb + (lm + 16 * w) * STR + 16 * mt + 4 * lg, acc);
        }
    }
    // ---------------- V = x Wv  (write V^T [e][tau^-1(f)]; pad cols exactly 0) ----------------
    // store col for f=16mt+4lg+r (mt=2ks+t): c = 32ks + 8lg + 4t + r
    {
        const unsigned short* wv = ws + 9 * 4096;
        short8 vw0 = *(const short8*)(wv + (lm + 16 * w) * 64 + 8 * lg);
        short8 vw1 = *(const short8*)(wv + (lm + 16 * w) * 64 + 8 * lg + 32);
        #pragma unroll
        for (int mt = 0; mt < 4; ++mt) {
            float4v acc = {0.f, 0.f, 0.f, 0.f};
            acc = MFMA(xf[mt][0], vw0, acc);
            acc = MFMA(xf[mt][1], vw1, acc);
            st_pack4(Vt + (lm + 16 * w) * STR + 32 * (mt >> 1) + 8 * lg + 4 * (mt & 1), acc);
        }
    }
    // ---------------- R = x Wr  (registers; wave owns f-tile w) ----------------
    float4v racc[4];
    {
        const unsigned short* wr = ws + 10 * 4096;
        #pragma unroll
        for (int nt = 0; nt < 4; ++nt) {
            short8 rw0 = *(const short8*)(wr + (lm + 16 * nt) * 64 + 8 * lg);
            short8 rw1 = *(const short8*)(wr + (lm + 16 * nt) * 64 + 8 * lg + 32);
            float4v acc = {0.f, 0.f, 0.f, 0.f};
            acc = MFMA(xf[w][0], rw0, acc);
            acc = MFMA(xf[w][1], rw1, acc);
            racc[nt] = acc;
        }
    }
    __syncthreads();   // barrier 2: Kb/Vt visible (the last barrier)

    // gamma/beta issued early to hide global latency under scores/softmax/PV
    float gm[4], bt[4];
    #pragma unroll
    for (int c = 0; c < 4; ++c) {
        gm[c] = gam_g[dom * 64 + 16 * c + lm];
        bt[c] = bet_g[dom * 64 + 16 * c + lm];
    }

    // ---------------- scores + softmax per head (all in wave's own f-block) ----------------
    // S^T[j][f] = sum_d K[j][d] Q[f][d]; lane holds j=16mt+4lg+r, f=16w+lm.
    // Pad rows j>=NF have score exactly 0 -> closed-form fixup sum -= 14*2^(-mx).
    short8 pa[2][2];   // PV A-frag: [head][k-slice]
    #pragma unroll
    for (int h = 0; h < 2; ++h) {
        float4v sacc[4];
        #pragma unroll
        for (int mt = 0; mt < 4; ++mt) {
            short8 kf = *(const short8*)(Kb + (lm + 16 * mt) * STR + 32 * h + 8 * lg);
            float4v z = {0.f, 0.f, 0.f, 0.f};
            sacc[mt] = MFMA(kf, qfrag[h], z);
        }
        float p[4][4];
        float mx = 0.f;   // pads guarantee max >= 0
        #pragma unroll
        for (int mt = 0; mt < 4; ++mt)
            #pragma unroll
            for (int r = 0; r < 4; ++r) {
                p[mt][r] = sacc[mt][r];
                mx = fmaxf(mx, p[mt][r]);
            }
        mx = fmaxf(mx, __shfl_xor(mx, 16));
        mx = fmaxf(mx, __shfl_xor(mx, 32));
        float sum = 0.f;
        #pragma unroll
        for (int mt = 0; mt < 4; ++mt)
            #pragma unroll
            for (int r = 0; r < 4; ++r) {
                float e = fexp2(p[mt][r] - mx);
                p[mt][r] = e; sum += e;
            }
        sum += __shfl_xor(sum, 16);
        sum += __shfl_xor(sum, 32);
        sum -= 14.f * fexp2(-mx);    // remove the 14 pad contributions
        const float ri = frcp(sum);
        // pack P into PV A-frag order: slice ks covers regs mt'=2ks,2ks+1
        #pragma unroll
        for (int ks = 0; ks < 2; ++ks) {
            union { unsigned short u[8]; short8 s; } r;
            #pragma unroll
            for (int r4 = 0; r4 < 4; ++r4) {
                r.u[r4]     = f2bf(p[2 * ks][r4] * ri);
                r.u[4 + r4] = f2bf(p[2 * ks + 1][r4] * ri);
            }
            pa[h][ks] = r.s;
        }
    }

    // ---------------- PV (+R as C-init): wave owns f-tile w ----------------
    float4v oacc[4];
    #pragma unroll
    for (int c = 0; c < 4; ++c) oacc[c] = racc[c];
    #pragma unroll
    for (int h = 0; h < 2; ++h)
        #pragma unroll
        for (int nt2 = 0; nt2 < 2; ++nt2) {
            const int c = 2 * h + nt2;
            short8 vf0 = *(const short8*)(Vt + (16 * c + lm) * STR + 8 * lg);
            short8 vf1 = *(const short8*)(Vt + (16 * c + lm) * STR + 8 * lg + 32);
            oacc[c] = MFMA(pa[h][0], vf0, oacc[c]);
            oacc[c] = MFMA(pa[h][1], vf1, oacc[c]);
        }

    // ---------------- relu + LayerNorm + store (4 independent shfl chains) ----------------
    float v[4][4], s1[4], s2[4];
    #pragma unroll
    for (int r = 0; r < 4; ++r) {
        #pragma unroll
        for (int c = 0; c < 4; ++c) v[r][c] = fmaxf(oacc[c][r], 0.f);
        s1[r] = v[r][0] + v[r][1] + v[r][2] + v[r][3];
        s2[r] = v[r][0]*v[r][0] + v[r][1]*v[r][1] + v[r][2]*v[r][2] + v[r][3]*v[r][3];
    }
    #pragma unroll
    for (int msk = 1; msk < 16; msk <<= 1) {
        #pragma unroll
        for (int r = 0; r < 4; ++r) {
            s1[r] += __shfl_xor(s1[r], msk);
            s2[r] += __shfl_xor(s2[r], msk);
        }
    }
    #pragma unroll
    for (int r = 0; r < 4; ++r) {
        const float mean = s1[r] * (1.f / 64.f);
        const float var  = s2[r] * (1.f / 64.f) - mean * mean;
        const float rs   = rsqrtf(var + LN_EPS);
        const int f = 4 * lg + r + 16 * w;
        if (f < NF) {
            float* op = out_g + (size_t)b * (NF * NE) + f * 64 + lm;
            #pragma unroll
            for (int c = 0; c < 4; ++c)
                op[16 * c] = (v[r][c] - mean) * rs * gm[c] + bt[c];
        }
    }
}

extern "C" void kernel_launch(void* const* d_in, const int* in_sizes, int n_in,
                              void* d_out, int out_size, void* d_ws, size_t ws_size,
                              hipStream_t stream) {
    const float* x   = (const float*)d_in[0];
    const int*   dom = (const int*)  d_in[1];
    const float* wq  = (const float*)d_in[2];
    const float* wk  = (const float*)d_in[3];
    const float* wv  = (const float*)d_in[4];
    const float* wr  = (const float*)d_in[5];
    const float* gam = (const float*)d_in[6];
    const float* bet = (const float*)d_in[7];
    unsigned short* ws = (unsigned short*)d_ws;
    float* out = (float*)d_out;

    hipLaunchKernelGGL(prep_weights, dim3(176), dim3(256), 0, stream, wq, wk, wv, wr, ws);
    hipLaunchKernelGGL(mdr_mfma, dim3(NB), dim3(256), 0, stream,
                       x, dom, ws, gam, bet, out);
}

// Round 8
// 121.621 us; speedup vs baseline: 1.5848x; 1.5848x over previous
//
#include <hip/hip_runtime.h>
#include <hip/hip_bf16.h>

#define NB    8192
#define NF    50
#define NE    64
#define STR   72            // LDS row stride in bf16 elems (144 B, 16B-aligned rows)

typedef __attribute__((ext_vector_type(8))) short short8;   // 8 x bf16 MFMA A/B frag (4 VGPR)
typedef __attribute__((ext_vector_type(4))) short short4v;  // 4 x bf16 packed store
typedef __attribute__((ext_vector_type(4))) float float4v;  // MFMA C/D frag

static constexpr float SM_C   = 0.25509667991878083f; // (1/sqrt(32)) * log2(e), folded into Wk
static constexpr float LN_EPS = 1e-6f;

#define MFMA(a, b, c) __builtin_amdgcn_mfma_f32_16x16x32_bf16((a), (b), (c), 0, 0, 0)

__device__ __forceinline__ unsigned short f2bf(float f) {
    return __bfloat16_as_ushort(__float2bfloat16(f));  // native RNE cvt
}

__device__ __forceinline__ void st_pack4(unsigned short* p, float4v v) {
    union { unsigned short u[4]; short4v s; } r;
    r.u[0] = f2bf(v.x); r.u[1] = f2bf(v.y); r.u[2] = f2bf(v.z); r.u[3] = f2bf(v.w);
    *(short4v*)p = r.s;   // ds_write_b64
}

__device__ __forceinline__ float fexp2(float x) {
#if __has_builtin(__builtin_amdgcn_exp2f)
    return __builtin_amdgcn_exp2f(x);
#else
    float r; asm("v_exp_f32 %0, %1" : "=v"(r) : "v"(x)); return r;
#endif
}

__device__ __forceinline__ float frcp(float x) {
#if __has_builtin(__builtin_amdgcn_rcpf)
    return __builtin_amdgcn_rcpf(x);
#else
    return 1.f / x;
#endif
}

// ---- prep: transpose all weights to bf16 [mat][o][e] = W[e][o] in d_ws ----
// slots 0..7 = Wq domains (o-PERMUTED, see pi below), 8 = Wk (pre-scaled by SM_C),
// 9 = Wv, 10 = Wr.
// pi: stored row o' holds original output-col pi(o') so the Q-projection's
// accumulator registers land exactly in score-MFMA B-fragment order.
__global__ void prep_weights(const float* __restrict__ wq, const float* __restrict__ wk,
                             const float* __restrict__ wv, const float* __restrict__ wr,
                             unsigned short* __restrict__ ws) {
    int i = blockIdx.x * 256 + threadIdx.x;
    if (i >= 11 * 4096) return;
    int m = i >> 12, t = i & 4095, o = t >> 6, e = t & 63;
    float v;
    if (m < 8) {
        int po = (o & 32) | ((o & 12) << 1) | (((o >> 4) & 1) << 2) | (o & 3);
        v = wq[(m * 64 + e) * 64 + po];
    }
    else if (m == 8) v = wk[e * 64 + o] * SM_C;   // fold softmax scale (and log2e) into K
    else if (m == 9) v = wv[e * 64 + o];
    else             v = wr[e * 64 + o];
    ws[i] = f2bf(v);
}

__global__ __launch_bounds__(256, 4)
void mdr_mfma(const float* __restrict__ x_g, const int* __restrict__ dom_g,
              const unsigned short* __restrict__ ws,
              const float* __restrict__ gam_g, const float* __restrict__ bet_g,
              float* __restrict__ out_g) {
    __shared__ __align__(16) unsigned short L[3 * NE * STR];   // 27648 B
    unsigned short* xs = L;                 // x rowmajor [64][STR]
    unsigned short* Kb = L + NE * STR;      // K rowmajor [j][d]
    unsigned short* Vt = L + 2 * NE * STR;  // V^T [e][tau-permuted j]

    const int tid = threadIdx.x;
    const int lm  = tid & 15;        // lane & 15
    const int lg  = (tid >> 4) & 3;  // lane >> 4 within wave
    const int w   = tid >> 6;        // wave 0..3
    const int b   = blockIdx.x;

    const int dom = dom_g[b] - 1;

    // ---------------- stage x (f32 -> bf16, rows >= NF zeroed) ----------------
    {
        const float* xb = x_g + (size_t)b * (NF * NE);
        #pragma unroll
        for (int it = 0; it < 4; ++it) {
            int s = tid + it * 256;          // 0..1023 : row = s>>4, c4 = s&15
            int r = s >> 4, c4 = s & 15;
            float4v v = {0.f, 0.f, 0.f, 0.f};
            if (r < NF) v = *(const float4v*)(xb + s * 4);
            st_pack4(xs + r * STR + c4 * 4, v);
        }
    }
    __syncthreads();   // barrier 1: xs staged

    // ---------------- V = x Wv FIRST, streaming x tiles (low reg pressure) ----------------
    // write V^T [e][tau^-1(f)]; pad cols exactly 0
    {
        const unsigned short* wv = ws + 9 * 4096;
        short8 vw0 = *(const short8*)(wv + (lm + 16 * w) * 64 + 8 * lg);
        short8 vw1 = *(const short8*)(wv + (lm + 16 * w) * 64 + 8 * lg + 32);
        #pragma unroll
        for (int mt = 0; mt < 4; ++mt) {
            short8 xv0 = *(const short8*)(xs + (lm + 16 * mt) * STR + 8 * lg);
            short8 xv1 = *(const short8*)(xs + (lm + 16 * mt) * STR + 8 * lg + 32);
            float4v acc = {0.f, 0.f, 0.f, 0.f};
            acc = MFMA(xv0, vw0, acc);
            acc = MFMA(xv1, vw1, acc);
            st_pack4(Vt + (lm + 16 * w) * STR + 32 * (mt >> 1) + 8 * lg + 4 * (mt & 1), acc);
        }
    }

    // ---------------- wave-own x fragment (lives until R-projection) ----------------
    short8 xfw0 = *(const short8*)(xs + (lm + 16 * w) * STR + 8 * lg);
    short8 xfw1 = *(const short8*)(xs + (lm + 16 * w) * STR + 8 * lg + 32);

    // ---------------- Q^T = Wq'^T x^T  (registers only; pi-permuted Wq) ----------------
    short8 qfrag[2];     // score B-frag per head
    {
        const unsigned short* wq = ws + dom * 4096;
        #pragma unroll
        for (int h = 0; h < 2; ++h) {
            float4v a0, a1;
            {
                short8 qw0 = *(const short8*)(wq + (lm + 16 * (2 * h)) * 64 + 8 * lg);
                short8 qw1 = *(const short8*)(wq + (lm + 16 * (2 * h)) * 64 + 8 * lg + 32);
                float4v z = {0.f, 0.f, 0.f, 0.f};
                z = MFMA(qw0, xfw0, z);
                a0 = MFMA(qw1, xfw1, z);
            }
            {
                short8 qw0 = *(const short8*)(wq + (lm + 16 * (2 * h + 1)) * 64 + 8 * lg);
                short8 qw1 = *(const short8*)(wq + (lm + 16 * (2 * h + 1)) * 64 + 8 * lg + 32);
                float4v z = {0.f, 0.f, 0.f, 0.f};
                z = MFMA(qw0, xfw0, z);
                a1 = MFMA(qw1, xfw1, z);
            }
            union { unsigned short u[8]; short8 s; } r;
            #pragma unroll
            for (int r4 = 0; r4 < 4; ++r4) {
                r.u[r4]     = f2bf(a0[r4]);
                r.u[4 + r4] = f2bf(a1[r4]);
            }
            qfrag[h] = r.s;
        }
    }
    // ---------------- K^T = Wk^T x^T  (write rowmajor K; rows >= NF exactly 0) ----------------
    {
        const unsigned short* wk = ws + 8 * 4096;
        #pragma unroll
        for (int mt = 0; mt < 4; ++mt) {
            short8 kw0 = *(const short8*)(wk + (lm + 16 * mt) * 64 + 8 * lg);
            short8 kw1 = *(const short8*)(wk + (lm + 16 * mt) * 64 + 8 * lg + 32);
            float4v acc = {0.f, 0.f, 0.f, 0.f};
            acc = MFMA(kw0, xfw0, acc);
            acc = MFMA(kw1, xfw1, acc);
            st_pack4(Kb + (lm + 16 * w) * STR + 16 * mt + 4 * lg, acc);
        }
    }
    __syncthreads();   // barrier 2: Kb/Vt visible (the last barrier)

    // ---------------- scores + softmax per head (wave's own f-block) ----------------
    // S^T[j][f]: lane holds j=16mt+4lg+r, f=16w+lm. Pad rows j>=NF are exactly 0
    // -> closed-form fixup sum -= 14*2^(-mx).
    short8 pa[2][2];   // PV A-frag: [head][k-slice]
    #pragma unroll
    for (int h = 0; h < 2; ++h) {
        float p[4][4];
        float mx = 0.f;   // pads guarantee max >= 0
        #pragma unroll
        for (int mt = 0; mt < 4; ++mt) {
            short8 kf = *(const short8*)(Kb + (lm + 16 * mt) * STR + 32 * h + 8 * lg);
            float4v z = {0.f, 0.f, 0.f, 0.f};
            float4v s = MFMA(kf, qfrag[h], z);
            #pragma unroll
            for (int r = 0; r < 4; ++r) {
                p[mt][r] = s[r];
                mx = fmaxf(mx, s[r]);
            }
        }
        mx = fmaxf(mx, __shfl_xor(mx, 16));
        mx = fmaxf(mx, __shfl_xor(mx, 32));
        float sum = 0.f;
        #pragma unroll
        for (int mt = 0; mt < 4; ++mt)
            #pragma unroll
            for (int r = 0; r < 4; ++r) {
                float e = fexp2(p[mt][r] - mx);
                p[mt][r] = e; sum += e;
            }
        sum += __shfl_xor(sum, 16);
        sum += __shfl_xor(sum, 32);
        sum -= 14.f * fexp2(-mx);    // remove the 14 pad contributions
        const float ri = frcp(sum);
        #pragma unroll
        for (int ks = 0; ks < 2; ++ks) {
            union { unsigned short u[8]; short8 s; } r;
            #pragma unroll
            for (int r4 = 0; r4 < 4; ++r4) {
                r.u[r4]     = f2bf(p[2 * ks][r4] * ri);
                r.u[4 + r4] = f2bf(p[2 * ks + 1][r4] * ri);
            }
            pa[h][ks] = r.s;
        }
    }

    // ---------------- PV: wave owns f-tile w (zero-init C) ----------------
    float4v oacc[4];
    #pragma unroll
    for (int c = 0; c < 4; ++c) { oacc[c].x = 0.f; oacc[c].y = 0.f; oacc[c].z = 0.f; oacc[c].w = 0.f; }
    #pragma unroll
    for (int h = 0; h < 2; ++h)
        #pragma unroll
        for (int nt2 = 0; nt2 < 2; ++nt2) {
            const int c = 2 * h + nt2;
            short8 vf0 = *(const short8*)(Vt + (16 * c + lm) * STR + 8 * lg);
            short8 vf1 = *(const short8*)(Vt + (16 * c + lm) * STR + 8 * lg + 32);
            oacc[c] = MFMA(pa[h][0], vf0, oacc[c]);
            oacc[c] = MFMA(pa[h][1], vf1, oacc[c]);
        }

    // ---------------- R = x Wr, accumulated into oacc (deferred; xfw still live) ----------------
    {
        const unsigned short* wr = ws + 10 * 4096;
        #pragma unroll
        for (int nt = 0; nt < 4; ++nt) {
            short8 rw0 = *(const short8*)(wr + (lm + 16 * nt) * 64 + 8 * lg);
            short8 rw1 = *(const short8*)(wr + (lm + 16 * nt) * 64 + 8 * lg + 32);
            oacc[nt] = MFMA(xfw0, rw0, oacc[nt]);
            oacc[nt] = MFMA(xfw1, rw1, oacc[nt]);
        }
    }

    // ---------------- relu + LayerNorm + store (4 independent shfl chains) ----------------
    float gm[4], bt[4];
    #pragma unroll
    for (int c = 0; c < 4; ++c) {
        gm[c] = gam_g[dom * 64 + 16 * c + lm];
        bt[c] = bet_g[dom * 64 + 16 * c + lm];
    }
    float v[4][4], s1[4], s2[4];
    #pragma unroll
    for (int r = 0; r < 4; ++r) {
        #pragma unroll
        for (int c = 0; c < 4; ++c) v[r][c] = fmaxf(oacc[c][r], 0.f);
        s1[r] = v[r][0] + v[r][1] + v[r][2] + v[r][3];
        s2[r] = v[r][0]*v[r][0] + v[r][1]*v[r][1] + v[r][2]*v[r][2] + v[r][3]*v[r][3];
    }
    #pragma unroll
    for (int msk = 1; msk < 16; msk <<= 1) {
        #pragma unroll
        for (int r = 0; r < 4; ++r) {
            s1[r] += __shfl_xor(s1[r], msk);
            s2[r] += __shfl_xor(s2[r], msk);
        }
    }
    #pragma unroll
    for (int r = 0; r < 4; ++r) {
        const float mean = s1[r] * (1.f / 64.f);
        const float var  = s2[r] * (1.f / 64.f) - mean * mean;
        const float rs   = rsqrtf(var + LN_EPS);
        const int f = 4 * lg + r + 16 * w;
        if (f < NF) {
            float* op = out_g + (size_t)b * (NF * NE) + f * 64 + lm;
            #pragma unroll
            for (int c = 0; c < 4; ++c)
                op[16 * c] = (v[r][c] - mean) * rs * gm[c] + bt[c];
        }
    }
}

extern "C" void kernel_launch(void* const* d_in, const int* in_sizes, int n_in,
                              void* d_out, int out_size, void* d_ws, size_t ws_size,
                              hipStream_t stream) {
    const float* x   = (const float*)d_in[0];
    const int*   dom = (const int*)  d_in[1];
    const float* wq  = (const float*)d_in[2];
    const float* wk  = (const float*)d_in[3];
    const float* wv  = (const float*)d_in[4];
    const float* wr  = (const float*)d_in[5];
    const float* gam = (const float*)d_in[6];
    const float* bet = (const float*)d_in[7];
    unsigned short* ws = (unsigned short*)d_ws;
    float* out = (float*)d_out;

    hipLaunchKernelGGL(prep_weights, dim3(176), dim3(256), 0, stream, wq, wk, wv, wr, ws);
    hipLaunchKernelGGL(mdr_mfma, dim3(NB), dim3(256), 0, stream,
                       x, dom, ws, gam, bet, out);
}

// Round 9
// 118.683 us; speedup vs baseline: 1.6241x; 1.0248x over previous
//
#include <hip/hip_runtime.h>
#include <hip/hip_bf16.h>

#define NB    8192
#define NF    50
#define NE    64
#define STR   72            // LDS row stride in bf16 elems (144 B, 16B-aligned rows)

typedef __attribute__((ext_vector_type(8))) short short8;   // 8 x bf16 MFMA A/B frag (4 VGPR)
typedef __attribute__((ext_vector_type(4))) short short4v;  // 4 x bf16 packed store
typedef __attribute__((ext_vector_type(4))) float float4v;  // MFMA C/D frag

static constexpr float SM_C   = 0.25509667991878083f; // (1/sqrt(32)) * log2(e), folded into Wk
static constexpr float LN_EPS = 1e-6f;

#define MFMA(a, b, c) __builtin_amdgcn_mfma_f32_16x16x32_bf16((a), (b), (c), 0, 0, 0)

__device__ __forceinline__ unsigned short f2bf(float f) {
    return __bfloat16_as_ushort(__float2bfloat16(f));  // native RNE cvt
}

__device__ __forceinline__ void st_pack4(unsigned short* p, float4v v) {
    union { unsigned short u[4]; short4v s; } r;
    r.u[0] = f2bf(v.x); r.u[1] = f2bf(v.y); r.u[2] = f2bf(v.z); r.u[3] = f2bf(v.w);
    *(short4v*)p = r.s;   // ds_write_b64
}

__device__ __forceinline__ float fexp2(float x) {
#if __has_builtin(__builtin_amdgcn_exp2f)
    return __builtin_amdgcn_exp2f(x);
#else
    float r; asm("v_exp_f32 %0, %1" : "=v"(r) : "v"(x)); return r;
#endif
}

__device__ __forceinline__ float frcp(float x) {
#if __has_builtin(__builtin_amdgcn_rcpf)
    return __builtin_amdgcn_rcpf(x);
#else
    return 1.f / x;
#endif
}

// ---- prep: transpose all weights to bf16 [mat][o][e] = W[e][o] in d_ws ----
// slots 0..7 = Wq domains (o-PERMUTED, see pi below), 8 = Wk (pre-scaled by SM_C),
// 9 = Wv, 10 = Wr.
// pi: stored row o' holds original output-col pi(o') so the Q-projection's
// accumulator registers land exactly in score-MFMA B-fragment order.
__global__ void prep_weights(const float* __restrict__ wq, const float* __restrict__ wk,
                             const float* __restrict__ wv, const float* __restrict__ wr,
                             unsigned short* __restrict__ ws) {
    int i = blockIdx.x * 256 + threadIdx.x;
    if (i >= 11 * 4096) return;
    int m = i >> 12, t = i & 4095, o = t >> 6, e = t & 63;
    float v;
    if (m < 8) {
        int po = (o & 32) | ((o & 12) << 1) | (((o >> 4) & 1) << 2) | (o & 3);
        v = wq[(m * 64 + e) * 64 + po];
    }
    else if (m == 8) v = wk[e * 64 + o] * SM_C;   // fold softmax scale (and log2e) into K
    else if (m == 9) v = wv[e * 64 + o];
    else             v = wr[e * 64 + o];
    ws[i] = f2bf(v);
}

__global__ __launch_bounds__(256, 5)
void mdr_mfma(const float* __restrict__ x_g, const int* __restrict__ dom_g,
              const unsigned short* __restrict__ ws,
              const float* __restrict__ gam_g, const float* __restrict__ bet_g,
              float* __restrict__ out_g) {
    __shared__ __align__(16) unsigned short L[3 * NE * STR];   // 27648 B -> 5 blocks/CU
    unsigned short* xs = L;                 // x rowmajor [64][STR]
    unsigned short* Kb = L + NE * STR;      // K rowmajor [j][d]
    unsigned short* Vt = L + 2 * NE * STR;  // V^T [e][tau-permuted j]

    const int tid = threadIdx.x;
    const int lm  = tid & 15;        // lane & 15
    const int lg  = (tid >> 4) & 3;  // lane >> 4 within wave
    const int w   = tid >> 6;        // wave 0..3
    const int b   = blockIdx.x;

    const int dom = dom_g[b] - 1;

    // ---------------- stage x (f32 -> bf16, rows >= NF zeroed) ----------------
    {
        const float* xb = x_g + (size_t)b * (NF * NE);
        #pragma unroll
        for (int it = 0; it < 4; ++it) {
            int s = tid + it * 256;          // 0..1023 : row = s>>4, c4 = s&15
            int r = s >> 4, c4 = s & 15;
            float4v v = {0.f, 0.f, 0.f, 0.f};
            if (r < NF) v = *(const float4v*)(xb + s * 4);
            st_pack4(xs + r * STR + c4 * 4, v);
        }
    }

    // ---------------- PRE-BARRIER weight prefetch (LDS-independent loads) ----
    // Issued here so their L1/L2 latency hides under the x-stage drain + barrier.
    short8 vw0, vw1, kw[4][2];
    {
        const unsigned short* wv = ws + 9 * 4096;
        vw0 = *(const short8*)(wv + (lm + 16 * w) * 64 + 8 * lg);
        vw1 = *(const short8*)(wv + (lm + 16 * w) * 64 + 8 * lg + 32);
        const unsigned short* wk = ws + 8 * 4096;
        #pragma unroll
        for (int mt = 0; mt < 4; ++mt) {
            kw[mt][0] = *(const short8*)(wk + (lm + 16 * mt) * 64 + 8 * lg);
            kw[mt][1] = *(const short8*)(wk + (lm + 16 * mt) * 64 + 8 * lg + 32);
        }
    }
    __syncthreads();   // barrier 1: xs staged

    // ---------------- V = x Wv, streaming x tiles (prefetched vw) ----------------
    // write V^T [e][tau^-1(f)]; pad cols exactly 0
    #pragma unroll
    for (int mt = 0; mt < 4; ++mt) {
        short8 xv0 = *(const short8*)(xs + (lm + 16 * mt) * STR + 8 * lg);
        short8 xv1 = *(const short8*)(xs + (lm + 16 * mt) * STR + 8 * lg + 32);
        float4v acc = {0.f, 0.f, 0.f, 0.f};
        acc = MFMA(xv0, vw0, acc);
        acc = MFMA(xv1, vw1, acc);
        st_pack4(Vt + (lm + 16 * w) * STR + 32 * (mt >> 1) + 8 * lg + 4 * (mt & 1), acc);
    }

    // ---------------- wave-own x fragment (lives until R-projection) ----------------
    short8 xfw0 = *(const short8*)(xs + (lm + 16 * w) * STR + 8 * lg);
    short8 xfw1 = *(const short8*)(xs + (lm + 16 * w) * STR + 8 * lg + 32);

    // ---------------- K^T = Wk^T x^T  (prefetched kw; rows >= NF exactly 0) ----------------
    #pragma unroll
    for (int mt = 0; mt < 4; ++mt) {
        float4v acc = {0.f, 0.f, 0.f, 0.f};
        acc = MFMA(kw[mt][0], xfw0, acc);
        acc = MFMA(kw[mt][1], xfw1, acc);
        st_pack4(Kb + (lm + 16 * w) * STR + 16 * mt + 4 * lg, acc);
    }

    // ---------------- Q^T = Wq'^T x^T  (registers only; pi-permuted Wq) ----------------
    short8 qfrag[2];     // score B-frag per head
    {
        const unsigned short* wq = ws + dom * 4096;
        #pragma unroll
        for (int h = 0; h < 2; ++h) {
            float4v a0, a1;
            {
                short8 qw0 = *(const short8*)(wq + (lm + 16 * (2 * h)) * 64 + 8 * lg);
                short8 qw1 = *(const short8*)(wq + (lm + 16 * (2 * h)) * 64 + 8 * lg + 32);
                float4v z = {0.f, 0.f, 0.f, 0.f};
                z = MFMA(qw0, xfw0, z);
                a0 = MFMA(qw1, xfw1, z);
            }
            {
                short8 qw0 = *(const short8*)(wq + (lm + 16 * (2 * h + 1)) * 64 + 8 * lg);
                short8 qw1 = *(const short8*)(wq + (lm + 16 * (2 * h + 1)) * 64 + 8 * lg + 32);
                float4v z = {0.f, 0.f, 0.f, 0.f};
                z = MFMA(qw0, xfw0, z);
                a1 = MFMA(qw1, xfw1, z);
            }
            union { unsigned short u[8]; short8 s; } r;
            #pragma unroll
            for (int r4 = 0; r4 < 4; ++r4) {
                r.u[r4]     = f2bf(a0[r4]);
                r.u[4 + r4] = f2bf(a1[r4]);
            }
            qfrag[h] = r.s;
        }
    }
    __syncthreads();   // barrier 2: Kb/Vt visible (the last barrier)

    // gamma/beta issued early to hide global latency under scores/softmax/PV
    float gm[4], bt[4];
    #pragma unroll
    for (int c = 0; c < 4; ++c) {
        gm[c] = gam_g[dom * 64 + 16 * c + lm];
        bt[c] = bet_g[dom * 64 + 16 * c + lm];
    }

    // ---------------- scores + softmax per head (wave's own f-block) ----------------
    // S^T[j][f]: lane holds j=16mt+4lg+r, f=16w+lm. Pad rows j>=NF are exactly 0
    // -> closed-form fixup sum -= 14*2^(-mx).
    short8 pa[2][2];   // PV A-frag: [head][k-slice]
    #pragma unroll
    for (int h = 0; h < 2; ++h) {
        float p[4][4];
        float mx = 0.f;   // pads guarantee max >= 0
        #pragma unroll
        for (int mt = 0; mt < 4; ++mt) {
            short8 kf = *(const short8*)(Kb + (lm + 16 * mt) * STR + 32 * h + 8 * lg);
            float4v z = {0.f, 0.f, 0.f, 0.f};
            float4v s = MFMA(kf, qfrag[h], z);
            #pragma unroll
            for (int r = 0; r < 4; ++r) {
                p[mt][r] = s[r];
                mx = fmaxf(mx, s[r]);
            }
        }
        mx = fmaxf(mx, __shfl_xor(mx, 16));
        mx = fmaxf(mx, __shfl_xor(mx, 32));
        float sum = 0.f;
        #pragma unroll
        for (int mt = 0; mt < 4; ++mt)
            #pragma unroll
            for (int r = 0; r < 4; ++r) {
                float e = fexp2(p[mt][r] - mx);
                p[mt][r] = e; sum += e;
            }
        sum += __shfl_xor(sum, 16);
        sum += __shfl_xor(sum, 32);
        sum -= 14.f * fexp2(-mx);    // remove the 14 pad contributions
        const float ri = frcp(sum);
        #pragma unroll
        for (int ks = 0; ks < 2; ++ks) {
            union { unsigned short u[8]; short8 s; } r;
            #pragma unroll
            for (int r4 = 0; r4 < 4; ++r4) {
                r.u[r4]     = f2bf(p[2 * ks][r4] * ri);
                r.u[4 + r4] = f2bf(p[2 * ks + 1][r4] * ri);
            }
            pa[h][ks] = r.s;
        }
    }

    // ---------------- PV: wave owns f-tile w (zero-init C) ----------------
    float4v oacc[4];
    #pragma unroll
    for (int c = 0; c < 4; ++c) { oacc[c].x = 0.f; oacc[c].y = 0.f; oacc[c].z = 0.f; oacc[c].w = 0.f; }
    #pragma unroll
    for (int h = 0; h < 2; ++h)
        #pragma unroll
        for (int nt2 = 0; nt2 < 2; ++nt2) {
            const int c = 2 * h + nt2;
            short8 vf0 = *(const short8*)(Vt + (16 * c + lm) * STR + 8 * lg);
            short8 vf1 = *(const short8*)(Vt + (16 * c + lm) * STR + 8 * lg + 32);
            oacc[c] = MFMA(pa[h][0], vf0, oacc[c]);
            oacc[c] = MFMA(pa[h][1], vf1, oacc[c]);
        }

    // ---------------- R = x Wr, accumulated into oacc (deferred; xfw still live) ----------------
    {
        const unsigned short* wr = ws + 10 * 4096;
        #pragma unroll
        for (int nt = 0; nt < 4; ++nt) {
            short8 rw0 = *(const short8*)(wr + (lm + 16 * nt) * 64 + 8 * lg);
            short8 rw1 = *(const short8*)(wr + (lm + 16 * nt) * 64 + 8 * lg + 32);
            oacc[nt] = MFMA(xfw0, rw0, oacc[nt]);
            oacc[nt] = MFMA(xfw1, rw1, oacc[nt]);
        }
    }

    // ---------------- relu + LayerNorm + store (4 independent shfl chains) ----------------
    float v[4][4], s1[4], s2[4];
    #pragma unroll
    for (int r = 0; r < 4; ++r) {
        #pragma unroll
        for (int c = 0; c < 4; ++c) v[r][c] = fmaxf(oacc[c][r], 0.f);
        s1[r] = v[r][0] + v[r][1] + v[r][2] + v[r][3];
        s2[r] = v[r][0]*v[r][0] + v[r][1]*v[r][1] + v[r][2]*v[r][2] + v[r][3]*v[r][3];
    }
    #pragma unroll
    for (int msk = 1; msk < 16; msk <<= 1) {
        #pragma unroll
        for (int r = 0; r < 4; ++r) {
            s1[r] += __shfl_xor(s1[r], msk);
            s2[r] += __shfl_xor(s2[r], msk);
        }
    }
    #pragma unroll
    for (int r = 0; r < 4; ++r) {
        const float mean = s1[r] * (1.f / 64.f);
        const float var  = s2[r] * (1.f / 64.f) - mean * mean;
        const float rs   = rsqrtf(var + LN_EPS);
        const int f = 4 * lg + r + 16 * w;
        if (f < NF) {
            float* op = out_g + (size_t)b * (NF * NE) + f * 64 + lm;
            #pragma unroll
            for (int c = 0; c < 4; ++c)
                op[16 * c] = (v[r][c] - mean) * rs * gm[c] + bt[c];
        }
    }
}

extern "C" void kernel_launch(void* const* d_in, const int* in_sizes, int n_in,
                              void* d_out, int out_size, void* d_ws, size_t ws_size,
                              hipStream_t stream) {
    const float* x   = (const float*)d_in[0];
    const int*   dom = (const int*)  d_in[1];
    const float* wq  = (const float*)d_in[2];
    const float* wk  = (const float*)d_in[3];
    const float* wv  = (const float*)d_in[4];
    const float* wr  = (const float*)d_in[5];
    const float* gam = (const float*)d_in[6];
    const float* bet = (const float*)d_in[7];
    unsigned short* ws = (unsigned short*)d_ws;
    float* out = (float*)d_out;

    hipLaunchKernelGGL(prep_weights, dim3(176), dim3(256), 0, stream, wq, wk, wv, wr, ws);
    hipLaunchKernelGGL(mdr_mfma, dim3(NB), dim3(256), 0, stream,
                       x, dom, ws, gam, bet, out);
}